// Round 5
// baseline (408.581 us; speedup 1.0000x reference)
//
#include <hip/hip_runtime.h>
#include <stdint.h>

typedef __attribute__((ext_vector_type(2))) __fp16 half2v;

#define TB 192

constexpr int Bn = 8, Cn = 256, Hn = 128, Wn = 192;
constexpr int TY = 4, ROWS = 12, LROW = 200, NOFF = 33;

// dy rows that carry offsets, their dx sets, and output-channel bases
// (reference order: dy outer -4..4, dx inner -4..4)
constexpr int DYt[7]   = {-4,-2,-1,0,1,2,4};
constexpr int NDXt[7]  = {5,5,3,7,3,5,5};
constexpr int DXt[7][7] = {
  {-4,-2, 0, 2, 4, 0, 0},
  {-4,-2, 0, 2, 4, 0, 0},
  {-1, 0, 1, 0, 0, 0, 0},
  {-4,-2,-1, 0, 1, 2, 4},
  {-1, 0, 1, 0, 0, 0, 0},
  {-4,-2, 0, 2, 4, 0, 0},
  {-4,-2, 0, 2, 4, 0, 0}};
constexpr int OBt[7]   = {0,5,10,13,20,23,28};

static __device__ __forceinline__ float dot2f(half2v a, half2v b, float c) {
#if __has_builtin(__builtin_amdgcn_fdot2)
  return __builtin_amdgcn_fdot2(a, b, c, false);
#else
  return c + (float)a.x * (float)b.x + (float)a.y * (float)b.y;
#endif
}

static __device__ __forceinline__ half2v pk2(float lo, float hi) {
  return __builtin_amdgcn_cvt_pkrtz(lo, hi);
}
static __device__ __forceinline__ half2v asH2(uint32_t u) {
  return __builtin_bit_cast(half2v, u);
}
static __device__ __forceinline__ uint32_t asU32(half2v h) {
  return __builtin_bit_cast(uint32_t, h);
}

__global__ __launch_bounds__(TB, 1)
void dcorr_kernel(const float* __restrict__ cur,
                  const float* __restrict__ prv,
                  float* __restrict__ out) {
  // prev halo tile, fp16x2-packed (2 channels per u32), double-buffered
  __shared__ __align__(16) uint32_t pb[2][ROWS * LROW];  // 19.2 KB
  __shared__ __align__(16) float    ssl[ROWS * LROW];    //  9.6 KB (invn_prev)

  const int t  = threadIdx.x;
  const int y0 = blockIdx.x * TY;
  const int b  = blockIdx.y;
  const int ty = t / 48;          // 0..3
  const int tx = (t % 48) * 4;    // 0..188 step 4
  const int y  = y0 + ty;
  const size_t plane = (size_t)Hn * Wn;  // 24576

  const float* curP = cur + ((size_t)b * Cn) * plane + (size_t)y * Wn + tx;
  const float* prvB = prv + ((size_t)b * Cn) * plane;

  // staging map: thread handles float4 slots f = k*TB + t over 12 rows x 48 f4
  int soff[3]; int goff[3]; bool sval[3];
  #pragma unroll
  for (int k = 0; k < 3; ++k) {
    int f  = k * TB + t;            // 0..575
    int r  = f / 48;                // halo row 0..11
    int c4 = f % 48;
    soff[k] = r * LROW + 4 + c4 * 4;
    int gy = y0 + r - 4;
    sval[k] = (gy >= 0) && (gy < Hn);
    int gyc = gy < 0 ? 0 : (gy > Hn - 1 ? Hn - 1 : gy);
    goff[k] = gyc * Wn + c4 * 4;
  }

  { // zero the 4-col pads on both LDS buffers (written once, persist)
    int bu = t / 96, rem = t % 96, r = rem / 8, ci = rem % 8;
    int col = ci < 4 ? ci : 192 + ci;   // 0..3 and 196..199
    pb[bu][r * LROW + col] = 0u;
  }

  float acc[NOFF][4];
  #pragma unroll
  for (int o = 0; o < NOFF; ++o) {
    acc[o][0] = 0.f; acc[o][1] = 0.f; acc[o][2] = 0.f; acc[o][3] = 0.f;
  }
  float ssc[4] = {0.f, 0.f, 0.f, 0.f};
  float ssp[12];
  #pragma unroll
  for (int i = 0; i < 12; ++i) ssp[i] = 0.f;

  // prefetch channel-pair 0
  float4 cf0, cf1, pf0[3], pf1[3];
  cf0 = *(const float4*)(curP);
  cf1 = *(const float4*)(curP + plane);
  #pragma unroll
  for (int k = 0; k < 3; ++k) {
    pf0[k] = *(const float4*)(prvB + goff[k]);
    pf1[k] = *(const float4*)(prvB + plane + goff[k]);
  }

  half2v a[4];
  for (int p = 0; p < 128; ++p) {
    // ---- pack curr (channels 2p,2p+1) + curr ss ----
    a[0] = pk2(cf0.x, cf1.x); a[1] = pk2(cf0.y, cf1.y);
    a[2] = pk2(cf0.z, cf1.z); a[3] = pk2(cf0.w, cf1.w);
    #pragma unroll
    for (int j = 0; j < 4; ++j) ssc[j] = dot2f(a[j], a[j], ssc[j]);

    // ---- pack prev halo, accumulate prev ss, write LDS buffer p&1 ----
    #pragma unroll
    for (int k = 0; k < 3; ++k) {
      float4 q0 = pf0[k], q1 = pf1[k];
      if (!sval[k]) { q0 = make_float4(0.f,0.f,0.f,0.f); q1 = q0; }
      half2v h0 = pk2(q0.x, q1.x), h1 = pk2(q0.y, q1.y);
      half2v hA = pk2(q0.z, q1.z), hB = pk2(q0.w, q1.w);
      ssp[k*4+0] = dot2f(h0, h0, ssp[k*4+0]);
      ssp[k*4+1] = dot2f(h1, h1, ssp[k*4+1]);
      ssp[k*4+2] = dot2f(hA, hA, ssp[k*4+2]);
      ssp[k*4+3] = dot2f(hB, hB, ssp[k*4+3]);
      uint4 wv = make_uint4(asU32(h0), asU32(h1), asU32(hA), asU32(hB));
      *(uint4*)&pb[p & 1][soff[k]] = wv;
    }

    // ---- prefetch next channel-pair ----
    if (p < 127) {
      curP += 2 * plane;
      const float* pp = prvB + (size_t)(2 * (p + 1)) * plane;
      cf0 = *(const float4*)(curP);
      cf1 = *(const float4*)(curP + plane);
      #pragma unroll
      for (int k = 0; k < 3; ++k) {
        pf0[k] = *(const float4*)(pp + goff[k]);
        pf1[k] = *(const float4*)(pp + plane + goff[k]);
      }
    }

    __syncthreads();  // buffer p&1 ready for all waves

    // ---- accumulate 33 offsets over this channel pair ----
    const uint32_t* Lb = pb[p & 1];
    #pragma unroll
    for (int r = 0; r < 7; ++r) {
      const int base = (ty + 4 + DYt[r]) * LROW + tx;  // covers gx = tx-4 .. tx+7
      uint4 q0 = *(const uint4*)&Lb[base];
      uint4 q1 = *(const uint4*)&Lb[base + 4];
      uint4 q2 = *(const uint4*)&Lb[base + 8];
      uint32_t pr[12] = {q0.x,q0.y,q0.z,q0.w, q1.x,q1.y,q1.z,q1.w, q2.x,q2.y,q2.z,q2.w};
      #pragma unroll
      for (int i = 0; i < 7; ++i) {
        if (i < NDXt[r]) {
          const int o  = OBt[r] + i;
          const int dx = DXt[r][i];
          #pragma unroll
          for (int px = 0; px < 4; ++px) {
            acc[o][px] = dot2f(a[px], asH2(pr[px + dx + 4]), acc[o][px]);
          }
        }
      }
    }
  }

  // ---- prev inverse norms -> LDS ----
  #pragma unroll
  for (int k = 0; k < 3; ++k) {
    #pragma unroll
    for (int j = 0; j < 4; ++j) {
      float inv = 1.0f / fmaxf(sqrtf(ssp[k*4+j]), 1e-12f);
      ssl[soff[k] + j] = inv;
    }
  }
  if (t < 96) {  // pads (OOB pixels): raw dot is exactly 0 there, value irrelevant
    int r = t / 8, ci = t % 8;
    int col = ci < 4 ? ci : 192 + ci;
    ssl[r * LROW + col] = 0.f;
  }
  __syncthreads();

  float invc[4];
  #pragma unroll
  for (int px = 0; px < 4; ++px) invc[px] = 1.0f / fmaxf(sqrtf(ssc[px]), 1e-12f);

  float* outB = out + ((size_t)b * NOFF) * plane + (size_t)y * Wn + tx;
  #pragma unroll
  for (int r = 0; r < 7; ++r) {
    const int base = (ty + 4 + DYt[r]) * LROW + tx;
    float4 f0 = *(const float4*)&ssl[base];
    float4 f1 = *(const float4*)&ssl[base + 4];
    float4 f2 = *(const float4*)&ssl[base + 8];
    float pr[12] = {f0.x,f0.y,f0.z,f0.w, f1.x,f1.y,f1.z,f1.w, f2.x,f2.y,f2.z,f2.w};
    #pragma unroll
    for (int i = 0; i < 7; ++i) {
      if (i < NDXt[r]) {
        const int o  = OBt[r] + i;
        const int dx = DXt[r][i];
        float4 v;
        v.x = acc[o][0] * invc[0] * pr[0 + dx + 4];
        v.y = acc[o][1] * invc[1] * pr[1 + dx + 4];
        v.z = acc[o][2] * invc[2] * pr[2 + dx + 4];
        v.w = acc[o][3] * invc[3] * pr[3 + dx + 4];
        *(float4*)(outB + (size_t)o * plane) = v;
      }
    }
  }
}

extern "C" void kernel_launch(void* const* d_in, const int* in_sizes, int n_in,
                              void* d_out, int out_size, void* d_ws, size_t ws_size,
                              hipStream_t stream) {
  (void)in_sizes; (void)n_in; (void)out_size; (void)d_ws; (void)ws_size;
  const float* cur = (const float*)d_in[0];
  const float* prv = (const float*)d_in[1];
  float* out = (float*)d_out;
  dim3 grid(Hn / TY, Bn);  // 32 x 8 = 256 blocks, 192 threads = 3 waves each
  dcorr_kernel<<<grid, TB, 0, stream>>>(cur, prv, out);
}